// Round 17
// baseline (236.109 us; speedup 1.0000x reference)
//
#include <hip/hip_runtime.h>
#include <hip/hip_bf16.h>

typedef unsigned short u16;
typedef unsigned int   u32;
typedef short  short8 __attribute__((ext_vector_type(8)));
typedef float  f32x4  __attribute__((ext_vector_type(4)));

#define NB    65536
#define XP    132
#define OFF1  ((size_t)NB * 128)
#define OFF2  (OFF1 + (size_t)NB * 4)

__device__ __forceinline__ u16 f2bf(float f) {
  __hip_bfloat16 b = __float2bfloat16(f);
  u16 u; __builtin_memcpy(&u, &b, 2); return u;
}
__device__ __forceinline__ float bf2f(u32 bits16) {
  union { u32 u; float f; } v; v.u = bits16 << 16; return v.f;
}
__device__ __forceinline__ u32 pk2(float a, float b) {
  return (u32)f2bf(a) | ((u32)f2bf(b) << 16);
}
__device__ __forceinline__ float unpk(u32 w, int hi) {
  return bf2f(hi ? (w >> 16) : (w & 0xffffu));
}
__device__ __forceinline__ float red16(float v) {
  v += __shfl_xor(v, 1); v += __shfl_xor(v, 2);
  v += __shfl_xor(v, 4); v += __shfl_xor(v, 8);
  return v;
}
// completes all outstanding LDS ops; compiler memory barrier (no HW barrier)
__device__ __forceinline__ void lds_fence() {
  asm volatile("s_waitcnt lgkmcnt(0)" ::: "memory");
}
// T5: boost wave priority through an MFMA cluster (independent-wave regime,
// m191 +4-7%); pure scheduler hint, cannot affect results.
__device__ __forceinline__ void prio_hi() { __builtin_amdgcn_s_setprio(1); }
__device__ __forceinline__ void prio_lo() { __builtin_amdgcn_s_setprio(0); }

// ---------------- weight pre-pack: 10 x [128][128] fp32 -> bf16 MFMA-B-fragment order
// packed[t]: t = w*16384 + nt*2048 + kt*512 + lane*8 + j
//   holds W_w[kt*32 + (lane>>4)*8 + j][nt*16 + (lane&15)]
__global__ void pack_w(const float* __restrict__ proj_w,
                       const float* __restrict__ in_proj_w,
                       const float* __restrict__ out_w,
                       const float* __restrict__ gate_w,
                       u16* __restrict__ wp) {
  int t = blockIdx.x * 256 + threadIdx.x;
  if (t >= 10 * 16384) return;
  int w = t >> 14, i = t & 16383;
  int nt = i >> 11, kt = (i >> 9) & 3, ln = (i >> 3) & 63, j = i & 7;
  int k = kt * 32 + ((ln >> 4) << 3) + j;
  int n = (nt << 4) + (ln & 15);
  float v;
  if (w < 4)       v = proj_w[((size_t)w << 14) + (k << 7) + n];
  else if (w < 7)  v = in_proj_w[k * 384 + ((w - 4) << 7) + n];
  else if (w == 7) v = out_w[(k << 7) + n];
  else             v = gate_w[(((w - 8) << 7) + k) * 128 + n];
  wp[t] = f2bf(v);
}

__device__ __forceinline__ short8 bfrag(const u16* __restrict__ wp, int w, int nt, int kt, int lane) {
  return *(const short8*)(wp + ((size_t)w << 14) + (size_t)((((nt << 2) + kt) << 6) + lane) * 8);
}

struct AF { short8 a[4]; };
__device__ __forceinline__ AF loadA(const u16 (*Ab)[XP], int row, int lgrp) {
  AF r;
  #pragma unroll
  for (int kt = 0; kt < 4; ++kt)
    r.a[kt] = *(const short8*)&Ab[row][kt * 32 + (lgrp << 3)];
  return r;
}
__device__ __forceinline__ f32x4 mmK128(const AF& A, const u16* __restrict__ wp, int w,
                                        int ntg, int lane, float bias) {
  f32x4 acc = {bias, bias, bias, bias};
  prio_hi();
  #pragma unroll
  for (int kt = 0; kt < 4; ++kt)
    acc = __builtin_amdgcn_mfma_f32_16x16x32_bf16(A.a[kt], bfrag(wp, w, ntg, kt, lane), acc, 0, 0, 0);
  prio_lo();
  return acc;
}

// One wave (64 threads) per 16-row tile. NO __syncthreads anywhere.
// R17 = R10 (best passing, replay-proven 175.6us) + T5 setprio around MFMA
// clusters. R10 structure: xls for x_1..3 (12.7 KB) + scr (4.2 KB); x_0 in
// regs (xcp0). Streaming traffic (h in, all outputs) NON-TEMPORAL so the
// 320 KB packed weight set stays L2-resident (R10: -13%).
// BANNED: min-waves launch_bounds arg (R8 spills; R16 replay-divergence when
// cap << live state).
__global__ __launch_bounds__(64) void fused_k(
    const float* __restrict__ h0, const float* __restrict__ h1,
    const float* __restrict__ h2, const float* __restrict__ h3,
    const u16* __restrict__ wp,
    const float* __restrict__ proj_b, const float* __restrict__ ctx_w,
    const float* __restrict__ in_proj_b, const float* __restrict__ out_b,
    const float* __restrict__ gate_b, const float* __restrict__ pool_w,
    const float* __restrict__ ln_g, const float* __restrict__ ln_b,
    float* __restrict__ out) {
  __shared__ __align__(16) u16 xls[3][16][XP];  // x_s (s=1..3), overwritten by fused f_s
  __shared__ __align__(16) u16 scr[16][XP];     // x_0 / context / o / attn_out transpose scratch

  const int lane  = threadIdx.x;     // 0..63
  const int lrow  = lane & 15;       // A-row / C-col-within-chunk
  const int lgrp  = lane >> 4;
  const int crow0 = lgrp << 2;       // C rows 4*lgrp + j
  const size_t r0w = (size_t)blockIdx.x * 16;

  const float* hp[4] = {h0, h1, h2, h3};

  // ---- P0: per source: h A-frags direct from global (NT), proj GEMM -> xls/xcp0, ctx logits
  float ctxl[4][4];
  AF Axs[4];
  u32 xcp0[8][2];
  #pragma unroll
  for (int s = 0; s < 4; ++s) {
    const float* __restrict__ hb = hp[s] + ((r0w + lrow) << 7) + (lgrp << 3);
    AF Ah;
    #pragma unroll
    for (int kt = 0; kt < 4; ++kt) {
      f32x4 va = __builtin_nontemporal_load((const f32x4*)(hb + kt * 32));
      f32x4 vb = __builtin_nontemporal_load((const f32x4*)(hb + kt * 32 + 4));
      u32 tmp[4] = {pk2(va[0], va[1]), pk2(va[2], va[3]), pk2(vb[0], vb[1]), pk2(vb[2], vb[3])};
      __builtin_memcpy(&Ah.a[kt], tmp, 16);
    }
    float lp[4] = {0.f, 0.f, 0.f, 0.f};
    #pragma unroll
    for (int nt = 0; nt < 8; ++nt) {
      int n = (nt << 4) + lrow;
      f32x4 acc = mmK128(Ah, wp, s, nt, lane, proj_b[(s << 7) + n]);
      float cwn = ctx_w[n];
      #pragma unroll
      for (int j = 0; j < 4; ++j) {
        lp[j] += acc[j] * cwn;
        if (s == 0) scr[crow0 + j][n] = f2bf(acc[j]);
        else        xls[s - 1][crow0 + j][n] = f2bf(acc[j]);
      }
      if (s == 0) {
        xcp0[nt][0] = pk2(acc[0], acc[1]);
        xcp0[nt][1] = pk2(acc[2], acc[3]);
      }
    }
    #pragma unroll
    for (int j = 0; j < 4; ++j) ctxl[s][j] = red16(lp[j]);
    if (s == 0) {
      lds_fence();
      Axs[0] = loadA(scr, lrow, lgrp);   // x_0 A-frags before scr is reused
    }
  }

  // ---- P1: ctx softmax per row (per-lane) + context -> scr
  float cw[4][4];
  #pragma unroll
  for (int j = 0; j < 4; ++j) {
    float l0 = ctxl[0][j], l1 = ctxl[1][j], l2 = ctxl[2][j], l3 = ctxl[3][j];
    float mx = fmaxf(fmaxf(l0, l1), fmaxf(l2, l3));
    float e0 = __expf(l0 - mx), e1 = __expf(l1 - mx), e2 = __expf(l2 - mx), e3 = __expf(l3 - mx);
    float inv = 1.f / (e0 + e1 + e2 + e3);
    cw[0][j] = e0 * inv; cw[1][j] = e1 * inv; cw[2][j] = e2 * inv; cw[3][j] = e3 * inv;
  }
  #pragma unroll
  for (int nt = 0; nt < 8; ++nt) {
    int n = (nt << 4) + lrow;
    #pragma unroll
    for (int j = 0; j < 4; ++j) {
      float v = cw[0][j] * unpk(xcp0[nt][j >> 1], j & 1)
              + cw[1][j] * bf2f((u32)xls[0][crow0 + j][n])
              + cw[2][j] * bf2f((u32)xls[1][crow0 + j][n])
              + cw[3][j] * bf2f((u32)xls[2][crow0 + j][n]);
      scr[crow0 + j][n] = f2bf(v);
    }
  }
  lds_fence();
  AF Ac = loadA(scr, lrow, lgrp);

  // ---- P2: q = context @ wq + bq (C-layout regs)
  float qf[8][4];
  #pragma unroll
  for (int nt = 0; nt < 8; ++nt) {
    int n = (nt << 4) + lrow;
    f32x4 acc = mmK128(Ac, wp, 4, nt, lane, in_proj_b[n]);
    #pragma unroll
    for (int j = 0; j < 4; ++j) qf[nt][j] = acc[j];
  }

  // ---- P3: K GEMM (s-inner, B shared) + scores
  lds_fence();
  #pragma unroll
  for (int s = 1; s < 4; ++s) Axs[s] = loadA(xls[s - 1], lrow, lgrp);
  float sc[4][4][4] = {};   // [s][j][h]
  #pragma unroll
  for (int nt = 0; nt < 8; ++nt) {
    int n = (nt << 4) + lrow;
    const int h = nt >> 1;
    float bk = in_proj_b[128 + n];
    f32x4 ak[4];
    #pragma unroll
    for (int s = 0; s < 4; ++s) ak[s] = (f32x4){bk, bk, bk, bk};
    prio_hi();
    #pragma unroll
    for (int kt = 0; kt < 4; ++kt) {
      short8 bf = bfrag(wp, 5, nt, kt, lane);
      #pragma unroll
      for (int s = 0; s < 4; ++s)
        ak[s] = __builtin_amdgcn_mfma_f32_16x16x32_bf16(Axs[s].a[kt], bf, ak[s], 0, 0, 0);
    }
    prio_lo();
    #pragma unroll
    for (int s = 0; s < 4; ++s)
      #pragma unroll
      for (int j = 0; j < 4; ++j)
        sc[s][j][h] += ak[s][j] * qf[nt][j];
  }
  #pragma unroll
  for (int s = 0; s < 4; ++s)
    #pragma unroll
    for (int j = 0; j < 4; ++j)
      #pragma unroll
      for (int h = 0; h < 4; ++h)
        sc[s][j][h] = red16(sc[s][j][h]);

  // ---- P4: attn softmax per lane + attn_weights out
  float aw[4][4][4];
  #pragma unroll
  for (int j = 0; j < 4; ++j)
    #pragma unroll
    for (int h = 0; h < 4; ++h) {
      const float scale = 0.17677669529663687f;  // 1/sqrt(32)
      float l0 = sc[0][j][h] * scale, l1 = sc[1][j][h] * scale;
      float l2 = sc[2][j][h] * scale, l3 = sc[3][j][h] * scale;
      float mx = fmaxf(fmaxf(l0, l1), fmaxf(l2, l3));
      float e0 = __expf(l0 - mx), e1 = __expf(l1 - mx), e2 = __expf(l2 - mx), e3 = __expf(l3 - mx);
      float inv = 1.f / (e0 + e1 + e2 + e3);
      aw[0][j][h] = e0 * inv; aw[1][j][h] = e1 * inv;
      aw[2][j][h] = e2 * inv; aw[3][j][h] = e3 * inv;
    }
  {
    float* awp = (float*)scr;   // scr dead (Ac in regs)
    if (lrow == 0) {
      #pragma unroll
      for (int s = 0; s < 4; ++s)
        #pragma unroll
        for (int j = 0; j < 4; ++j)
          awp[((crow0 + j) << 2) + s] =
            0.25f * (aw[s][j][0] + aw[s][j][1] + aw[s][j][2] + aw[s][j][3]);
    }
    lds_fence();
    __builtin_nontemporal_store(awp[lane], &out[OFF1 + (r0w << 2) + lane]);
  }

  // ---- P5: V GEMM (s-inner) + o -> scr
  {
    float oa[8][4] = {};
    #pragma unroll
    for (int nt = 0; nt < 8; ++nt) {
      int n = (nt << 4) + lrow;
      const int h = nt >> 1;
      float bv = in_proj_b[256 + n];
      f32x4 av[4];
      #pragma unroll
      for (int s = 0; s < 4; ++s) av[s] = (f32x4){bv, bv, bv, bv};
      prio_hi();
      #pragma unroll
      for (int kt = 0; kt < 4; ++kt) {
        short8 bf = bfrag(wp, 6, nt, kt, lane);
        #pragma unroll
        for (int s = 0; s < 4; ++s)
          av[s] = __builtin_amdgcn_mfma_f32_16x16x32_bf16(Axs[s].a[kt], bf, av[s], 0, 0, 0);
      }
      prio_lo();
      #pragma unroll
      for (int s = 0; s < 4; ++s)
        #pragma unroll
        for (int j = 0; j < 4; ++j)
          oa[nt][j] += aw[s][j][h] * av[s][j];
    }
    #pragma unroll
    for (int nt = 0; nt < 8; ++nt) {
      int n = (nt << 4) + lrow;
      #pragma unroll
      for (int j = 0; j < 4; ++j) scr[crow0 + j][n] = f2bf(oa[nt][j]);
    }
  }
  lds_fence();
  AF Ao = loadA(scr, lrow, lgrp);

  // ---- P6: attn_out = o @ out_w + out_b; fp32 C-layout regs + scr for Aa frags
  float aoreg[8][4];
  #pragma unroll
  for (int nt = 0; nt < 8; ++nt) {
    int n = (nt << 4) + lrow;
    f32x4 acc = mmK128(Ao, wp, 7, nt, lane, out_b[n]);
    #pragma unroll
    for (int j = 0; j < 4; ++j) {
      scr[crow0 + j][n] = f2bf(acc[j]);
      aoreg[nt][j] = acc[j];
    }
  }
  lds_fence();
  AF Aa = loadA(scr, lrow, lgrp);

  // ---- P7: gate. aacc = gate_b + ao @ W9 kept FP32, then per-s + x @ W8 (fp32 chain)
  f32x4 aacc[8];
  #pragma unroll
  for (int nt = 0; nt < 8; ++nt) {
    int n = (nt << 4) + lrow;
    float gb = gate_b[n];
    f32x4 t = {gb, gb, gb, gb};
    prio_hi();
    #pragma unroll
    for (int kt = 0; kt < 4; ++kt)
      t = __builtin_amdgcn_mfma_f32_16x16x32_bf16(Aa.a[kt], bfrag(wp, 9, nt, kt, lane), t, 0, 0, 0);
    prio_lo();
    aacc[nt] = t;
  }
  float sm[4][4] = {}, sq[4][4] = {};
  #pragma unroll
  for (int nt = 0; nt < 8; ++nt) {
    int n = (nt << 4) + lrow;
    short8 bf8[4];
    #pragma unroll
    for (int kt = 0; kt < 4; ++kt) bf8[kt] = bfrag(wp, 8, nt, kt, lane);
    #pragma unroll
    for (int s = 0; s < 4; ++s) {
      f32x4 acc = aacc[nt];
      prio_hi();
      #pragma unroll
      for (int kt = 0; kt < 4; ++kt)
        acc = __builtin_amdgcn_mfma_f32_16x16x32_bf16(Axs[s].a[kt], bf8[kt], acc, 0, 0, 0);
      prio_lo();
      float f[4];
      #pragma unroll
      for (int j = 0; j < 4; ++j) {
        float g = 1.f / (1.f + __expf(-acc[j]));
        __builtin_nontemporal_store(g, &out[OFF2 + (((r0w + crow0 + j) << 2) + s) * 128 + n]);
        float xv = (s == 0) ? unpk(xcp0[nt][j >> 1], j & 1)
                            : bf2f((u32)xls[s - 1][crow0 + j][n]);
        f[j] = g * aoreg[nt][j] + (1.f - g) * xv;
        sm[s][j] += f[j];
        sq[s][j] += f[j] * f[j];
        if (s > 0) xls[s - 1][crow0 + j][n] = f2bf(f[j]);   // overwrite x with fused
      }
      if (s == 0) {
        xcp0[nt][0] = pk2(f[0], f[1]);
        xcp0[nt][1] = pk2(f[2], f[3]);
      }
    }
  }
  float mean_[4][4], rstd_[4][4];
  #pragma unroll
  for (int s = 0; s < 4; ++s)
    #pragma unroll
    for (int j = 0; j < 4; ++j) {
      float ts = red16(sm[s][j]);
      float tq = red16(sq[s][j]);
      float mean = ts * 0.0078125f;
      float var  = tq * 0.0078125f - mean * mean;
      mean_[s][j] = mean;
      rstd_[s][j] = rsqrtf(var + 1e-5f);
    }

  // ---- P8: pool logits (fp32 fn from bf16 f) + softmax + pooled out
  float lngv[8], lnbv[8], pwvv[8];
  #pragma unroll
  for (int nt = 0; nt < 8; ++nt) {
    int n = (nt << 4) + lrow;
    lngv[nt] = ln_g[n]; lnbv[nt] = ln_b[n]; pwvv[nt] = pool_w[n];
  }
  float pp[4][4] = {};
  #pragma unroll
  for (int nt = 0; nt < 8; ++nt) {
    int n = (nt << 4) + lrow;
    #pragma unroll
    for (int s = 0; s < 4; ++s)
      #pragma unroll
      for (int j = 0; j < 4; ++j) {
        float f  = (s == 0) ? unpk(xcp0[nt][j >> 1], j & 1)
                            : bf2f((u32)xls[s - 1][crow0 + j][n]);
        float fn = (f - mean_[s][j]) * rstd_[s][j] * lngv[nt] + lnbv[nt];
        pp[s][j] += fn * pwvv[nt];
      }
  }
  float pw[4][4];
  #pragma unroll
  for (int j = 0; j < 4; ++j) {
    float l0 = red16(pp[0][j]), l1 = red16(pp[1][j]);
    float l2 = red16(pp[2][j]), l3 = red16(pp[3][j]);
    float mx = fmaxf(fmaxf(l0, l1), fmaxf(l2, l3));
    float e0 = __expf(l0 - mx), e1 = __expf(l1 - mx), e2 = __expf(l2 - mx), e3 = __expf(l3 - mx);
    float inv = 1.f / (e0 + e1 + e2 + e3);
    pw[0][j] = e0 * inv; pw[1][j] = e1 * inv; pw[2][j] = e2 * inv; pw[3][j] = e3 * inv;
  }
  #pragma unroll
  for (int nt = 0; nt < 8; ++nt) {
    int n = (nt << 4) + lrow;
    #pragma unroll
    for (int j = 0; j < 4; ++j) {
      float acc = 0.f;
      #pragma unroll
      for (int s = 0; s < 4; ++s) {
        float f  = (s == 0) ? unpk(xcp0[nt][j >> 1], j & 1)
                            : bf2f((u32)xls[s - 1][crow0 + j][n]);
        float fn = (f - mean_[s][j]) * rstd_[s][j] * lngv[nt] + lnbv[nt];
        acc += pw[s][j] * fn;
      }
      __builtin_nontemporal_store(acc, &out[((r0w + crow0 + j) << 7) + n]);
    }
  }
}

extern "C" void kernel_launch(void* const* d_in, const int* in_sizes, int n_in,
                              void* d_out, int out_size, void* d_ws, size_t ws_size,
                              hipStream_t stream) {
  const float* h0        = (const float*)d_in[0];
  const float* h1        = (const float*)d_in[1];
  const float* h2        = (const float*)d_in[2];
  const float* h3        = (const float*)d_in[3];
  const float* proj_w    = (const float*)d_in[4];
  const float* proj_b    = (const float*)d_in[5];
  const float* ctx_w     = (const float*)d_in[6];
  const float* in_proj_w = (const float*)d_in[8];
  const float* in_proj_b = (const float*)d_in[9];
  const float* out_w     = (const float*)d_in[10];
  const float* out_b     = (const float*)d_in[11];
  const float* gate_w    = (const float*)d_in[12];
  const float* gate_b    = (const float*)d_in[13];
  const float* pool_w    = (const float*)d_in[14];
  const float* ln_g      = (const float*)d_in[16];
  const float* ln_b      = (const float*)d_in[17];
  u16* wp = (u16*)d_ws;

  pack_w<<<640, 256, 0, stream>>>(proj_w, in_proj_w, out_w, gate_w, wp);
  fused_k<<<NB / 16, 64, 0, stream>>>(h0, h1, h2, h3, wp,
                                      proj_b, ctx_w, in_proj_b, out_b, gate_b,
                                      pool_w, ln_g, ln_b, (float*)d_out);
}

// Round 18
// 175.275 us; speedup vs baseline: 1.3471x; 1.3471x over previous
//
#include <hip/hip_runtime.h>
#include <hip/hip_bf16.h>

typedef unsigned short u16;
typedef unsigned int   u32;
typedef short  short8 __attribute__((ext_vector_type(8)));
typedef float  f32x4  __attribute__((ext_vector_type(4)));

#define NB    65536
#define XP    132
#define OFF1  ((size_t)NB * 128)
#define OFF2  (OFF1 + (size_t)NB * 4)

__device__ __forceinline__ u16 f2bf(float f) {
  __hip_bfloat16 b = __float2bfloat16(f);
  u16 u; __builtin_memcpy(&u, &b, 2); return u;
}
__device__ __forceinline__ float bf2f(u32 bits16) {
  union { u32 u; float f; } v; v.u = bits16 << 16; return v.f;
}
__device__ __forceinline__ u32 pk2(float a, float b) {
  return (u32)f2bf(a) | ((u32)f2bf(b) << 16);
}
__device__ __forceinline__ float unpk(u32 w, int hi) {
  return bf2f(hi ? (w >> 16) : (w & 0xffffu));
}
__device__ __forceinline__ float red16(float v) {
  v += __shfl_xor(v, 1); v += __shfl_xor(v, 2);
  v += __shfl_xor(v, 4); v += __shfl_xor(v, 8);
  return v;
}
// completes all outstanding LDS ops; compiler memory barrier (no HW barrier)
__device__ __forceinline__ void lds_fence() {
  asm volatile("s_waitcnt lgkmcnt(0)" ::: "memory");
}

// ---------------- weight pre-pack: 10 x [128][128] fp32 -> bf16 MFMA-B-fragment order
// packed[t]: t = w*16384 + nt*2048 + kt*512 + lane*8 + j
//   holds W_w[kt*32 + (lane>>4)*8 + j][nt*16 + (lane&15)]
__global__ void pack_w(const float* __restrict__ proj_w,
                       const float* __restrict__ in_proj_w,
                       const float* __restrict__ out_w,
                       const float* __restrict__ gate_w,
                       u16* __restrict__ wp) {
  int t = blockIdx.x * 256 + threadIdx.x;
  if (t >= 10 * 16384) return;
  int w = t >> 14, i = t & 16383;
  int nt = i >> 11, kt = (i >> 9) & 3, ln = (i >> 3) & 63, j = i & 7;
  int k = kt * 32 + ((ln >> 4) << 3) + j;
  int n = (nt << 4) + (ln & 15);
  float v;
  if (w < 4)       v = proj_w[((size_t)w << 14) + (k << 7) + n];
  else if (w < 7)  v = in_proj_w[k * 384 + ((w - 4) << 7) + n];
  else if (w == 7) v = out_w[(k << 7) + n];
  else             v = gate_w[(((w - 8) << 7) + k) * 128 + n];
  wp[t] = f2bf(v);
}

__device__ __forceinline__ short8 bfrag(const u16* __restrict__ wp, int w, int nt, int kt, int lane) {
  return *(const short8*)(wp + ((size_t)w << 14) + (size_t)((((nt << 2) + kt) << 6) + lane) * 8);
}

struct AF { short8 a[4]; };
__device__ __forceinline__ AF loadA(const u16 (*Ab)[XP], int row, int lgrp) {
  AF r;
  #pragma unroll
  for (int kt = 0; kt < 4; ++kt)
    r.a[kt] = *(const short8*)&Ab[row][kt * 32 + (lgrp << 3)];
  return r;
}
__device__ __forceinline__ f32x4 mmK128(const AF& A, const u16* __restrict__ wp, int w,
                                        int ntg, int lane, float bias) {
  f32x4 acc = {bias, bias, bias, bias};
  #pragma unroll
  for (int kt = 0; kt < 4; ++kt)
    acc = __builtin_amdgcn_mfma_f32_16x16x32_bf16(A.a[kt], bfrag(wp, w, ntg, kt, lane), acc, 0, 0, 0);
  return acc;
}

// One wave (64 threads) per 16-row tile. NO __syncthreads anywhere.
// R18 = R10 restored exactly (best measured: 175.6us, replay-proven).
// LDS: xls for x_1..3 (12.7 KB) + scr (4.2 KB). x_0 lives in registers (xcp0).
// Streaming traffic (h in, all outputs) is NON-TEMPORAL so the 320 KB packed
// weight set stays L2-resident (R10: -13% vs R9).
// Falsified levers (do not reintroduce): min-waves launch_bounds (R8 spills,
// R16 replay-divergence), 4-wave shared blocks (R11), LDS weight staging at
// 1 block/CU (R12), VGPR dieting (R13), rolled loops (R15), setprio (R17).
__global__ __launch_bounds__(64) void fused_k(
    const float* __restrict__ h0, const float* __restrict__ h1,
    const float* __restrict__ h2, const float* __restrict__ h3,
    const u16* __restrict__ wp,
    const float* __restrict__ proj_b, const float* __restrict__ ctx_w,
    const float* __restrict__ in_proj_b, const float* __restrict__ out_b,
    const float* __restrict__ gate_b, const float* __restrict__ pool_w,
    const float* __restrict__ ln_g, const float* __restrict__ ln_b,
    float* __restrict__ out) {
  __shared__ __align__(16) u16 xls[3][16][XP];  // x_s (s=1..3), overwritten by fused f_s
  __shared__ __align__(16) u16 scr[16][XP];     // x_0 / context / o / attn_out transpose scratch

  const int lane  = threadIdx.x;     // 0..63
  const int lrow  = lane & 15;       // A-row / C-col-within-chunk
  const int lgrp  = lane >> 4;
  const int crow0 = lgrp << 2;       // C rows 4*lgrp + j
  const size_t r0w = (size_t)blockIdx.x * 16;

  const float* hp[4] = {h0, h1, h2, h3};

  // ---- P0: per source: h A-frags direct from global (NT), proj GEMM -> xls/xcp0, ctx logits
  float ctxl[4][4];
  AF Axs[4];
  u32 xcp0[8][2];
  #pragma unroll
  for (int s = 0; s < 4; ++s) {
    const float* __restrict__ hb = hp[s] + ((r0w + lrow) << 7) + (lgrp << 3);
    AF Ah;
    #pragma unroll
    for (int kt = 0; kt < 4; ++kt) {
      f32x4 va = __builtin_nontemporal_load((const f32x4*)(hb + kt * 32));
      f32x4 vb = __builtin_nontemporal_load((const f32x4*)(hb + kt * 32 + 4));
      u32 tmp[4] = {pk2(va[0], va[1]), pk2(va[2], va[3]), pk2(vb[0], vb[1]), pk2(vb[2], vb[3])};
      __builtin_memcpy(&Ah.a[kt], tmp, 16);
    }
    float lp[4] = {0.f, 0.f, 0.f, 0.f};
    #pragma unroll
    for (int nt = 0; nt < 8; ++nt) {
      int n = (nt << 4) + lrow;
      f32x4 acc = mmK128(Ah, wp, s, nt, lane, proj_b[(s << 7) + n]);
      float cwn = ctx_w[n];
      #pragma unroll
      for (int j = 0; j < 4; ++j) {
        lp[j] += acc[j] * cwn;
        if (s == 0) scr[crow0 + j][n] = f2bf(acc[j]);
        else        xls[s - 1][crow0 + j][n] = f2bf(acc[j]);
      }
      if (s == 0) {
        xcp0[nt][0] = pk2(acc[0], acc[1]);
        xcp0[nt][1] = pk2(acc[2], acc[3]);
      }
    }
    #pragma unroll
    for (int j = 0; j < 4; ++j) ctxl[s][j] = red16(lp[j]);
    if (s == 0) {
      lds_fence();
      Axs[0] = loadA(scr, lrow, lgrp);   // x_0 A-frags before scr is reused
    }
  }

  // ---- P1: ctx softmax per row (per-lane) + context -> scr
  float cw[4][4];
  #pragma unroll
  for (int j = 0; j < 4; ++j) {
    float l0 = ctxl[0][j], l1 = ctxl[1][j], l2 = ctxl[2][j], l3 = ctxl[3][j];
    float mx = fmaxf(fmaxf(l0, l1), fmaxf(l2, l3));
    float e0 = __expf(l0 - mx), e1 = __expf(l1 - mx), e2 = __expf(l2 - mx), e3 = __expf(l3 - mx);
    float inv = 1.f / (e0 + e1 + e2 + e3);
    cw[0][j] = e0 * inv; cw[1][j] = e1 * inv; cw[2][j] = e2 * inv; cw[3][j] = e3 * inv;
  }
  #pragma unroll
  for (int nt = 0; nt < 8; ++nt) {
    int n = (nt << 4) + lrow;
    #pragma unroll
    for (int j = 0; j < 4; ++j) {
      float v = cw[0][j] * unpk(xcp0[nt][j >> 1], j & 1)
              + cw[1][j] * bf2f((u32)xls[0][crow0 + j][n])
              + cw[2][j] * bf2f((u32)xls[1][crow0 + j][n])
              + cw[3][j] * bf2f((u32)xls[2][crow0 + j][n]);
      scr[crow0 + j][n] = f2bf(v);
    }
  }
  lds_fence();
  AF Ac = loadA(scr, lrow, lgrp);

  // ---- P2: q = context @ wq + bq (C-layout regs)
  float qf[8][4];
  #pragma unroll
  for (int nt = 0; nt < 8; ++nt) {
    int n = (nt << 4) + lrow;
    f32x4 acc = mmK128(Ac, wp, 4, nt, lane, in_proj_b[n]);
    #pragma unroll
    for (int j = 0; j < 4; ++j) qf[nt][j] = acc[j];
  }

  // ---- P3: K GEMM (s-inner, B shared) + scores
  lds_fence();
  #pragma unroll
  for (int s = 1; s < 4; ++s) Axs[s] = loadA(xls[s - 1], lrow, lgrp);
  float sc[4][4][4] = {};   // [s][j][h]
  #pragma unroll
  for (int nt = 0; nt < 8; ++nt) {
    int n = (nt << 4) + lrow;
    const int h = nt >> 1;
    float bk = in_proj_b[128 + n];
    f32x4 ak[4];
    #pragma unroll
    for (int s = 0; s < 4; ++s) ak[s] = (f32x4){bk, bk, bk, bk};
    #pragma unroll
    for (int kt = 0; kt < 4; ++kt) {
      short8 bf = bfrag(wp, 5, nt, kt, lane);
      #pragma unroll
      for (int s = 0; s < 4; ++s)
        ak[s] = __builtin_amdgcn_mfma_f32_16x16x32_bf16(Axs[s].a[kt], bf, ak[s], 0, 0, 0);
    }
    #pragma unroll
    for (int s = 0; s < 4; ++s)
      #pragma unroll
      for (int j = 0; j < 4; ++j)
        sc[s][j][h] += ak[s][j] * qf[nt][j];
  }
  #pragma unroll
  for (int s = 0; s < 4; ++s)
    #pragma unroll
    for (int j = 0; j < 4; ++j)
      #pragma unroll
      for (int h = 0; h < 4; ++h)
        sc[s][j][h] = red16(sc[s][j][h]);

  // ---- P4: attn softmax per lane + attn_weights out
  float aw[4][4][4];
  #pragma unroll
  for (int j = 0; j < 4; ++j)
    #pragma unroll
    for (int h = 0; h < 4; ++h) {
      const float scale = 0.17677669529663687f;  // 1/sqrt(32)
      float l0 = sc[0][j][h] * scale, l1 = sc[1][j][h] * scale;
      float l2 = sc[2][j][h] * scale, l3 = sc[3][j][h] * scale;
      float mx = fmaxf(fmaxf(l0, l1), fmaxf(l2, l3));
      float e0 = __expf(l0 - mx), e1 = __expf(l1 - mx), e2 = __expf(l2 - mx), e3 = __expf(l3 - mx);
      float inv = 1.f / (e0 + e1 + e2 + e3);
      aw[0][j][h] = e0 * inv; aw[1][j][h] = e1 * inv;
      aw[2][j][h] = e2 * inv; aw[3][j][h] = e3 * inv;
    }
  {
    float* awp = (float*)scr;   // scr dead (Ac in regs)
    if (lrow == 0) {
      #pragma unroll
      for (int s = 0; s < 4; ++s)
        #pragma unroll
        for (int j = 0; j < 4; ++j)
          awp[((crow0 + j) << 2) + s] =
            0.25f * (aw[s][j][0] + aw[s][j][1] + aw[s][j][2] + aw[s][j][3]);
    }
    lds_fence();
    __builtin_nontemporal_store(awp[lane], &out[OFF1 + (r0w << 2) + lane]);
  }

  // ---- P5: V GEMM (s-inner) + o -> scr
  {
    float oa[8][4] = {};
    #pragma unroll
    for (int nt = 0; nt < 8; ++nt) {
      int n = (nt << 4) + lrow;
      const int h = nt >> 1;
      float bv = in_proj_b[256 + n];
      f32x4 av[4];
      #pragma unroll
      for (int s = 0; s < 4; ++s) av[s] = (f32x4){bv, bv, bv, bv};
      #pragma unroll
      for (int kt = 0; kt < 4; ++kt) {
        short8 bf = bfrag(wp, 6, nt, kt, lane);
        #pragma unroll
        for (int s = 0; s < 4; ++s)
          av[s] = __builtin_amdgcn_mfma_f32_16x16x32_bf16(Axs[s].a[kt], bf, av[s], 0, 0, 0);
      }
      #pragma unroll
      for (int s = 0; s < 4; ++s)
        #pragma unroll
        for (int j = 0; j < 4; ++j)
          oa[nt][j] += aw[s][j][h] * av[s][j];
    }
    #pragma unroll
    for (int nt = 0; nt < 8; ++nt) {
      int n = (nt << 4) + lrow;
      #pragma unroll
      for (int j = 0; j < 4; ++j) scr[crow0 + j][n] = f2bf(oa[nt][j]);
    }
  }
  lds_fence();
  AF Ao = loadA(scr, lrow, lgrp);

  // ---- P6: attn_out = o @ out_w + out_b; fp32 C-layout regs + scr for Aa frags
  float aoreg[8][4];
  #pragma unroll
  for (int nt = 0; nt < 8; ++nt) {
    int n = (nt << 4) + lrow;
    f32x4 acc = mmK128(Ao, wp, 7, nt, lane, out_b[n]);
    #pragma unroll
    for (int j = 0; j < 4; ++j) {
      scr[crow0 + j][n] = f2bf(acc[j]);
      aoreg[nt][j] = acc[j];
    }
  }
  lds_fence();
  AF Aa = loadA(scr, lrow, lgrp);

  // ---- P7: gate. aacc = gate_b + ao @ W9 kept FP32, then per-s + x @ W8 (fp32 chain)
  f32x4 aacc[8];
  #pragma unroll
  for (int nt = 0; nt < 8; ++nt) {
    int n = (nt << 4) + lrow;
    float gb = gate_b[n];
    f32x4 t = {gb, gb, gb, gb};
    #pragma unroll
    for (int kt = 0; kt < 4; ++kt)
      t = __builtin_amdgcn_mfma_f32_16x16x32_bf16(Aa.a[kt], bfrag(wp, 9, nt, kt, lane), t, 0, 0, 0);
    aacc[nt] = t;
  }
  float sm[4][4] = {}, sq[4][4] = {};
  #pragma unroll
  for (int nt = 0; nt < 8; ++nt) {
    int n = (nt << 4) + lrow;
    short8 bf8[4];
    #pragma unroll
    for (int kt = 0; kt < 4; ++kt) bf8[kt] = bfrag(wp, 8, nt, kt, lane);
    #pragma unroll
    for (int s = 0; s < 4; ++s) {
      f32x4 acc = aacc[nt];
      #pragma unroll
      for (int kt = 0; kt < 4; ++kt)
        acc = __builtin_amdgcn_mfma_f32_16x16x32_bf16(Axs[s].a[kt], bf8[kt], acc, 0, 0, 0);
      float f[4];
      #pragma unroll
      for (int j = 0; j < 4; ++j) {
        float g = 1.f / (1.f + __expf(-acc[j]));
        __builtin_nontemporal_store(g, &out[OFF2 + (((r0w + crow0 + j) << 2) + s) * 128 + n]);
        float xv = (s == 0) ? unpk(xcp0[nt][j >> 1], j & 1)
                            : bf2f((u32)xls[s - 1][crow0 + j][n]);
        f[j] = g * aoreg[nt][j] + (1.f - g) * xv;
        sm[s][j] += f[j];
        sq[s][j] += f[j] * f[j];
        if (s > 0) xls[s - 1][crow0 + j][n] = f2bf(f[j]);   // overwrite x with fused
      }
      if (s == 0) {
        xcp0[nt][0] = pk2(f[0], f[1]);
        xcp0[nt][1] = pk2(f[2], f[3]);
      }
    }
  }
  float mean_[4][4], rstd_[4][4];
  #pragma unroll
  for (int s = 0; s < 4; ++s)
    #pragma unroll
    for (int j = 0; j < 4; ++j) {
      float ts = red16(sm[s][j]);
      float tq = red16(sq[s][j]);
      float mean = ts * 0.0078125f;
      float var  = tq * 0.0078125f - mean * mean;
      mean_[s][j] = mean;
      rstd_[s][j] = rsqrtf(var + 1e-5f);
    }

  // ---- P8: pool logits (fp32 fn from bf16 f) + softmax + pooled out
  float lngv[8], lnbv[8], pwvv[8];
  #pragma unroll
  for (int nt = 0; nt < 8; ++nt) {
    int n = (nt << 4) + lrow;
    lngv[nt] = ln_g[n]; lnbv[nt] = ln_b[n]; pwvv[nt] = pool_w[n];
  }
  float pp[4][4] = {};
  #pragma unroll
  for (int nt = 0; nt < 8; ++nt) {
    int n = (nt << 4) + lrow;
    #pragma unroll
    for (int s = 0; s < 4; ++s)
      #pragma unroll
      for (int j = 0; j < 4; ++j) {
        float f  = (s == 0) ? unpk(xcp0[nt][j >> 1], j & 1)
                            : bf2f((u32)xls[s - 1][crow0 + j][n]);
        float fn = (f - mean_[s][j]) * rstd_[s][j] * lngv[nt] + lnbv[nt];
        pp[s][j] += fn * pwvv[nt];
      }
  }
  float pw[4][4];
  #pragma unroll
  for (int j = 0; j < 4; ++j) {
    float l0 = red16(pp[0][j]), l1 = red16(pp[1][j]);
    float l2 = red16(pp[2][j]), l3 = red16(pp[3][j]);
    float mx = fmaxf(fmaxf(l0, l1), fmaxf(l2, l3));
    float e0 = __expf(l0 - mx), e1 = __expf(l1 - mx), e2 = __expf(l2 - mx), e3 = __expf(l3 - mx);
    float inv = 1.f / (e0 + e1 + e2 + e3);
    pw[0][j] = e0 * inv; pw[1][j] = e1 * inv; pw[2][j] = e2 * inv; pw[3][j] = e3 * inv;
  }
  #pragma unroll
  for (int nt = 0; nt < 8; ++nt) {
    int n = (nt << 4) + lrow;
    #pragma unroll
    for (int j = 0; j < 4; ++j) {
      float acc = 0.f;
      #pragma unroll
      for (int s = 0; s < 4; ++s) {
        float f  = (s == 0) ? unpk(xcp0[nt][j >> 1], j & 1)
                            : bf2f((u32)xls[s - 1][crow0 + j][n]);
        float fn = (f - mean_[s][j]) * rstd_[s][j] * lngv[nt] + lnbv[nt];
        acc += pw[s][j] * fn;
      }
      __builtin_nontemporal_store(acc, &out[((r0w + crow0 + j) << 7) + n]);
    }
  }
}

extern "C" void kernel_launch(void* const* d_in, const int* in_sizes, int n_in,
                              void* d_out, int out_size, void* d_ws, size_t ws_size,
                              hipStream_t stream) {
  const float* h0        = (const float*)d_in[0];
  const float* h1        = (const float*)d_in[1];
  const float* h2        = (const float*)d_in[2];
  const float* h3        = (const float*)d_in[3];
  const float* proj_w    = (const float*)d_in[4];
  const float* proj_b    = (const float*)d_in[5];
  const float* ctx_w     = (const float*)d_in[6];
  const float* in_proj_w = (const float*)d_in[8];
  const float* in_proj_b = (const float*)d_in[9];
  const float* out_w     = (const float*)d_in[10];
  const float* out_b     = (const float*)d_in[11];
  const float* gate_w    = (const float*)d_in[12];
  const float* gate_b    = (const float*)d_in[13];
  const float* pool_w    = (const float*)d_in[14];
  const float* ln_g      = (const float*)d_in[16];
  const float* ln_b      = (const float*)d_in[17];
  u16* wp = (u16*)d_ws;

  pack_w<<<640, 256, 0, stream>>>(proj_w, in_proj_w, out_w, gate_w, wp);
  fused_k<<<NB / 16, 64, 0, stream>>>(h0, h1, h2, h3, wp,
                                      proj_b, ctx_w, in_proj_b, out_b, gate_b,
                                      pool_w, ln_g, ln_b, (float*)d_out);
}

// Round 19
// 171.659 us; speedup vs baseline: 1.3755x; 1.0211x over previous
//
#include <hip/hip_runtime.h>
#include <hip/hip_bf16.h>

typedef unsigned short u16;
typedef unsigned int   u32;
typedef short  short8 __attribute__((ext_vector_type(8)));
typedef float  f32x4  __attribute__((ext_vector_type(4)));

#define NB    65536
#define XP    132
#define OFF1  ((size_t)NB * 128)
#define OFF2  (OFF1 + (size_t)NB * 4)

__device__ __forceinline__ u16 f2bf(float f) {
  __hip_bfloat16 b = __float2bfloat16(f);
  u16 u; __builtin_memcpy(&u, &b, 2); return u;
}
__device__ __forceinline__ float bf2f(u32 bits16) {
  union { u32 u; float f; } v; v.u = bits16 << 16; return v.f;
}
__device__ __forceinline__ u32 pk2(float a, float b) {
  return (u32)f2bf(a) | ((u32)f2bf(b) << 16);
}
__device__ __forceinline__ float unpk(u32 w, int hi) {
  return bf2f(hi ? (w >> 16) : (w & 0xffffu));
}
__device__ __forceinline__ float red16(float v) {
  v += __shfl_xor(v, 1); v += __shfl_xor(v, 2);
  v += __shfl_xor(v, 4); v += __shfl_xor(v, 8);
  return v;
}
// completes all outstanding LDS ops; compiler memory barrier (no HW barrier)
__device__ __forceinline__ void lds_fence() {
  asm volatile("s_waitcnt lgkmcnt(0)" ::: "memory");
}

// ---------------- weight pre-pack: 10 x [128][128] fp32 -> bf16 MFMA-B-fragment order
// packed[t]: t = w*16384 + nt*2048 + kt*512 + lane*8 + j
//   holds W_w[kt*32 + (lane>>4)*8 + j][nt*16 + (lane&15)]
__global__ void pack_w(const float* __restrict__ proj_w,
                       const float* __restrict__ in_proj_w,
                       const float* __restrict__ out_w,
                       const float* __restrict__ gate_w,
                       u16* __restrict__ wp) {
  int t = blockIdx.x * 256 + threadIdx.x;
  if (t >= 10 * 16384) return;
  int w = t >> 14, i = t & 16383;
  int nt = i >> 11, kt = (i >> 9) & 3, ln = (i >> 3) & 63, j = i & 7;
  int k = kt * 32 + ((ln >> 4) << 3) + j;
  int n = (nt << 4) + (ln & 15);
  float v;
  if (w < 4)       v = proj_w[((size_t)w << 14) + (k << 7) + n];
  else if (w < 7)  v = in_proj_w[k * 384 + ((w - 4) << 7) + n];
  else if (w == 7) v = out_w[(k << 7) + n];
  else             v = gate_w[(((w - 8) << 7) + k) * 128 + n];
  wp[t] = f2bf(v);
}

// All 4 kt B-fragments of one (w, nt) loaded as a batch BEFORE the MFMA chain:
// forces MLP=4 instead of the load->mfma->load serialization (R13 diagnosis).
struct BF4 { short8 b[4]; };
__device__ __forceinline__ BF4 loadB4(const u16* __restrict__ wp, int w, int nt, int lane) {
  const u16* base = wp + ((size_t)w << 14) + ((size_t)(nt << 2) << 9) + ((size_t)lane << 3);
  BF4 r;
  #pragma unroll
  for (int kt = 0; kt < 4; ++kt)
    r.b[kt] = *(const short8*)(base + (kt << 9));
  return r;
}
struct AF { short8 a[4]; };
__device__ __forceinline__ AF loadA(const u16 (*Ab)[XP], int row, int lgrp) {
  AF r;
  #pragma unroll
  for (int kt = 0; kt < 4; ++kt)
    r.a[kt] = *(const short8*)&Ab[row][kt * 32 + (lgrp << 3)];
  return r;
}
__device__ __forceinline__ f32x4 mm4(const AF& A, const BF4& B, f32x4 acc) {
  #pragma unroll
  for (int kt = 0; kt < 4; ++kt)
    acc = __builtin_amdgcn_mfma_f32_16x16x32_bf16(A.a[kt], B.b[kt], acc, 0, 0, 0);
  return acc;
}

// One wave (64 threads) per 16-row tile. NO __syncthreads anywhere.
// R19 = R14 restored exactly (session best: 171.7us, passed, replay-stable).
// = R10 structure + batched/prefetched weight-fragment loads (MLP 1 -> 4-8).
// NT streaming hints kept (R10: -13%). No min-waves launch_bounds arg (R8: spills).
// Falsified levers (do not reintroduce): min-waves launch_bounds (R8/R16),
// 4-wave shared blocks (R11), LDS weight staging at 1 block/CU (R12),
// VGPR dieting (R13), rolled loops (R15), setprio (R17).
__global__ __launch_bounds__(64) void fused_k(
    const float* __restrict__ h0, const float* __restrict__ h1,
    const float* __restrict__ h2, const float* __restrict__ h3,
    const u16* __restrict__ wp,
    const float* __restrict__ proj_b, const float* __restrict__ ctx_w,
    const float* __restrict__ in_proj_b, const float* __restrict__ out_b,
    const float* __restrict__ gate_b, const float* __restrict__ pool_w,
    const float* __restrict__ ln_g, const float* __restrict__ ln_b,
    float* __restrict__ out) {
  __shared__ __align__(16) u16 xls[3][16][XP];  // x_s (s=1..3), overwritten by fused f_s
  __shared__ __align__(16) u16 scr[16][XP];     // x_0 / context / o / attn_out transpose scratch

  const int lane  = threadIdx.x;     // 0..63
  const int lrow  = lane & 15;       // A-row / C-col-within-chunk
  const int lgrp  = lane >> 4;
  const int crow0 = lgrp << 2;       // C rows 4*lgrp + j
  const size_t r0w = (size_t)blockIdx.x * 16;

  const float* hp[4] = {h0, h1, h2, h3};

  // ---- P0: per source: h A-frags direct from global (NT), proj GEMM -> xls/xcp0, ctx logits
  float ctxl[4][4];
  AF Axs[4];
  u32 xcp0[8][2];
  #pragma unroll
  for (int s = 0; s < 4; ++s) {
    const float* __restrict__ hb = hp[s] + ((r0w + lrow) << 7) + (lgrp << 3);
    AF Ah;
    #pragma unroll
    for (int kt = 0; kt < 4; ++kt) {
      f32x4 va = __builtin_nontemporal_load((const f32x4*)(hb + kt * 32));
      f32x4 vb = __builtin_nontemporal_load((const f32x4*)(hb + kt * 32 + 4));
      u32 tmp[4] = {pk2(va[0], va[1]), pk2(va[2], va[3]), pk2(vb[0], vb[1]), pk2(vb[2], vb[3])};
      __builtin_memcpy(&Ah.a[kt], tmp, 16);
    }
    float lp[4] = {0.f, 0.f, 0.f, 0.f};
    BF4 cb = loadB4(wp, s, 0, lane);
    #pragma unroll
    for (int nt = 0; nt < 8; ++nt) {
      BF4 nb;
      if (nt < 7) nb = loadB4(wp, s, nt + 1, lane);
      int n = (nt << 4) + lrow;
      float pb = proj_b[(s << 7) + n];
      f32x4 acc = {pb, pb, pb, pb};
      acc = mm4(Ah, cb, acc);
      float cwn = ctx_w[n];
      #pragma unroll
      for (int j = 0; j < 4; ++j) {
        lp[j] += acc[j] * cwn;
        if (s == 0) scr[crow0 + j][n] = f2bf(acc[j]);
        else        xls[s - 1][crow0 + j][n] = f2bf(acc[j]);
      }
      if (s == 0) {
        xcp0[nt][0] = pk2(acc[0], acc[1]);
        xcp0[nt][1] = pk2(acc[2], acc[3]);
      }
      if (nt < 7) cb = nb;
    }
    #pragma unroll
    for (int j = 0; j < 4; ++j) ctxl[s][j] = red16(lp[j]);
    if (s == 0) {
      lds_fence();
      Axs[0] = loadA(scr, lrow, lgrp);   // x_0 A-frags before scr is reused
    }
  }

  // ---- P1: ctx softmax per row (per-lane) + context -> scr
  float cw[4][4];
  #pragma unroll
  for (int j = 0; j < 4; ++j) {
    float l0 = ctxl[0][j], l1 = ctxl[1][j], l2 = ctxl[2][j], l3 = ctxl[3][j];
    float mx = fmaxf(fmaxf(l0, l1), fmaxf(l2, l3));
    float e0 = __expf(l0 - mx), e1 = __expf(l1 - mx), e2 = __expf(l2 - mx), e3 = __expf(l3 - mx);
    float inv = 1.f / (e0 + e1 + e2 + e3);
    cw[0][j] = e0 * inv; cw[1][j] = e1 * inv; cw[2][j] = e2 * inv; cw[3][j] = e3 * inv;
  }
  #pragma unroll
  for (int nt = 0; nt < 8; ++nt) {
    int n = (nt << 4) + lrow;
    #pragma unroll
    for (int j = 0; j < 4; ++j) {
      float v = cw[0][j] * unpk(xcp0[nt][j >> 1], j & 1)
              + cw[1][j] * bf2f((u32)xls[0][crow0 + j][n])
              + cw[2][j] * bf2f((u32)xls[1][crow0 + j][n])
              + cw[3][j] * bf2f((u32)xls[2][crow0 + j][n]);
      scr[crow0 + j][n] = f2bf(v);
    }
  }
  lds_fence();
  AF Ac = loadA(scr, lrow, lgrp);

  // ---- P2: q = context @ wq + bq (C-layout regs)
  float qf[8][4];
  {
    BF4 cb = loadB4(wp, 4, 0, lane);
    #pragma unroll
    for (int nt = 0; nt < 8; ++nt) {
      BF4 nb;
      if (nt < 7) nb = loadB4(wp, 4, nt + 1, lane);
      int n = (nt << 4) + lrow;
      float bq = in_proj_b[n];
      f32x4 acc = {bq, bq, bq, bq};
      acc = mm4(Ac, cb, acc);
      #pragma unroll
      for (int j = 0; j < 4; ++j) qf[nt][j] = acc[j];
      if (nt < 7) cb = nb;
    }
  }

  // ---- P3: K GEMM (s-inner, B shared) + scores
  lds_fence();
  #pragma unroll
  for (int s = 1; s < 4; ++s) Axs[s] = loadA(xls[s - 1], lrow, lgrp);
  float sc[4][4][4] = {};   // [s][j][h]
  {
    BF4 cb = loadB4(wp, 5, 0, lane);
    #pragma unroll
    for (int nt = 0; nt < 8; ++nt) {
      BF4 nb;
      if (nt < 7) nb = loadB4(wp, 5, nt + 1, lane);
      int n = (nt << 4) + lrow;
      const int h = nt >> 1;
      float bk = in_proj_b[128 + n];
      f32x4 ak[4];
      #pragma unroll
      for (int s = 0; s < 4; ++s) ak[s] = (f32x4){bk, bk, bk, bk};
      #pragma unroll
      for (int kt = 0; kt < 4; ++kt)
        #pragma unroll
        for (int s = 0; s < 4; ++s)
          ak[s] = __builtin_amdgcn_mfma_f32_16x16x32_bf16(Axs[s].a[kt], cb.b[kt], ak[s], 0, 0, 0);
      #pragma unroll
      for (int s = 0; s < 4; ++s)
        #pragma unroll
        for (int j = 0; j < 4; ++j)
          sc[s][j][h] += ak[s][j] * qf[nt][j];
      if (nt < 7) cb = nb;
    }
  }
  #pragma unroll
  for (int s = 0; s < 4; ++s)
    #pragma unroll
    for (int j = 0; j < 4; ++j)
      #pragma unroll
      for (int h = 0; h < 4; ++h)
        sc[s][j][h] = red16(sc[s][j][h]);

  // ---- P4: attn softmax per lane + attn_weights out
  float aw[4][4][4];
  #pragma unroll
  for (int j = 0; j < 4; ++j)
    #pragma unroll
    for (int h = 0; h < 4; ++h) {
      const float scale = 0.17677669529663687f;  // 1/sqrt(32)
      float l0 = sc[0][j][h] * scale, l1 = sc[1][j][h] * scale;
      float l2 = sc[2][j][h] * scale, l3 = sc[3][j][h] * scale;
      float mx = fmaxf(fmaxf(l0, l1), fmaxf(l2, l3));
      float e0 = __expf(l0 - mx), e1 = __expf(l1 - mx), e2 = __expf(l2 - mx), e3 = __expf(l3 - mx);
      float inv = 1.f / (e0 + e1 + e2 + e3);
      aw[0][j][h] = e0 * inv; aw[1][j][h] = e1 * inv;
      aw[2][j][h] = e2 * inv; aw[3][j][h] = e3 * inv;
    }
  {
    float* awp = (float*)scr;   // scr dead (Ac in regs)
    if (lrow == 0) {
      #pragma unroll
      for (int s = 0; s < 4; ++s)
        #pragma unroll
        for (int j = 0; j < 4; ++j)
          awp[((crow0 + j) << 2) + s] =
            0.25f * (aw[s][j][0] + aw[s][j][1] + aw[s][j][2] + aw[s][j][3]);
    }
    lds_fence();
    __builtin_nontemporal_store(awp[lane], &out[OFF1 + (r0w << 2) + lane]);
  }

  // ---- P5: V GEMM (s-inner) + o -> scr
  {
    float oa[8][4] = {};
    BF4 cb = loadB4(wp, 6, 0, lane);
    #pragma unroll
    for (int nt = 0; nt < 8; ++nt) {
      BF4 nb;
      if (nt < 7) nb = loadB4(wp, 6, nt + 1, lane);
      int n = (nt << 4) + lrow;
      const int h = nt >> 1;
      float bv = in_proj_b[256 + n];
      f32x4 av[4];
      #pragma unroll
      for (int s = 0; s < 4; ++s) av[s] = (f32x4){bv, bv, bv, bv};
      #pragma unroll
      for (int kt = 0; kt < 4; ++kt)
        #pragma unroll
        for (int s = 0; s < 4; ++s)
          av[s] = __builtin_amdgcn_mfma_f32_16x16x32_bf16(Axs[s].a[kt], cb.b[kt], av[s], 0, 0, 0);
      #pragma unroll
      for (int s = 0; s < 4; ++s)
        #pragma unroll
        for (int j = 0; j < 4; ++j)
          oa[nt][j] += aw[s][j][h] * av[s][j];
      if (nt < 7) cb = nb;
    }
    #pragma unroll
    for (int nt = 0; nt < 8; ++nt) {
      int n = (nt << 4) + lrow;
      #pragma unroll
      for (int j = 0; j < 4; ++j) scr[crow0 + j][n] = f2bf(oa[nt][j]);
    }
  }
  lds_fence();
  AF Ao = loadA(scr, lrow, lgrp);

  // ---- P6: attn_out = o @ out_w + out_b; fp32 C-layout regs + scr for Aa frags
  float aoreg[8][4];
  {
    BF4 cb = loadB4(wp, 7, 0, lane);
    #pragma unroll
    for (int nt = 0; nt < 8; ++nt) {
      BF4 nb;
      if (nt < 7) nb = loadB4(wp, 7, nt + 1, lane);
      int n = (nt << 4) + lrow;
      float bo = out_b[n];
      f32x4 acc = {bo, bo, bo, bo};
      acc = mm4(Ao, cb, acc);
      #pragma unroll
      for (int j = 0; j < 4; ++j) {
        scr[crow0 + j][n] = f2bf(acc[j]);
        aoreg[nt][j] = acc[j];
      }
      if (nt < 7) cb = nb;
    }
  }
  lds_fence();
  AF Aa = loadA(scr, lrow, lgrp);

  // ---- P7: gate. Per nt: batch-load W9+W8 frags (8 loads, MLP=8), fp32 chain
  float sm[4][4] = {}, sq[4][4] = {};
  #pragma unroll
  for (int nt = 0; nt < 8; ++nt) {
    int n = (nt << 4) + lrow;
    BF4 c9 = loadB4(wp, 9, nt, lane);
    BF4 c8 = loadB4(wp, 8, nt, lane);
    float gb = gate_b[n];
    f32x4 tt = {gb, gb, gb, gb};
    tt = mm4(Aa, c9, tt);
    #pragma unroll
    for (int s = 0; s < 4; ++s) {
      f32x4 acc = mm4(Axs[s], c8, tt);
      float f[4];
      #pragma unroll
      for (int j = 0; j < 4; ++j) {
        float g = 1.f / (1.f + __expf(-acc[j]));
        __builtin_nontemporal_store(g, &out[OFF2 + (((r0w + crow0 + j) << 2) + s) * 128 + n]);
        float xv = (s == 0) ? unpk(xcp0[nt][j >> 1], j & 1)
                            : bf2f((u32)xls[s - 1][crow0 + j][n]);
        f[j] = g * aoreg[nt][j] + (1.f - g) * xv;
        sm[s][j] += f[j];
        sq[s][j] += f[j] * f[j];
        if (s > 0) xls[s - 1][crow0 + j][n] = f2bf(f[j]);   // overwrite x with fused
      }
      if (s == 0) {
        xcp0[nt][0] = pk2(f[0], f[1]);
        xcp0[nt][1] = pk2(f[2], f[3]);
      }
    }
  }
  float mean_[4][4], rstd_[4][4];
  #pragma unroll
  for (int s = 0; s < 4; ++s)
    #pragma unroll
    for (int j = 0; j < 4; ++j) {
      float ts = red16(sm[s][j]);
      float tq = red16(sq[s][j]);
      float mean = ts * 0.0078125f;
      float var  = tq * 0.0078125f - mean * mean;
      mean_[s][j] = mean;
      rstd_[s][j] = rsqrtf(var + 1e-5f);
    }

  // ---- P8: pool logits (fp32 fn from bf16 f) + softmax + pooled out
  float lngv[8], lnbv[8], pwvv[8];
  #pragma unroll
  for (int nt = 0; nt < 8; ++nt) {
    int n = (nt << 4) + lrow;
    lngv[nt] = ln_g[n]; lnbv[nt] = ln_b[n]; pwvv[nt] = pool_w[n];
  }
  float pp[4][4] = {};
  #pragma unroll
  for (int nt = 0; nt < 8; ++nt) {
    int n = (nt << 4) + lrow;
    #pragma unroll
    for (int s = 0; s < 4; ++s)
      #pragma unroll
      for (int j = 0; j < 4; ++j) {
        float f  = (s == 0) ? unpk(xcp0[nt][j >> 1], j & 1)
                            : bf2f((u32)xls[s - 1][crow0 + j][n]);
        float fn = (f - mean_[s][j]) * rstd_[s][j] * lngv[nt] + lnbv[nt];
        pp[s][j] += fn * pwvv[nt];
      }
  }
  float pw[4][4];
  #pragma unroll
  for (int j = 0; j < 4; ++j) {
    float l0 = red16(pp[0][j]), l1 = red16(pp[1][j]);
    float l2 = red16(pp[2][j]), l3 = red16(pp[3][j]);
    float mx = fmaxf(fmaxf(l0, l1), fmaxf(l2, l3));
    float e0 = __expf(l0 - mx), e1 = __expf(l1 - mx), e2 = __expf(l2 - mx), e3 = __expf(l3 - mx);
    float inv = 1.f / (e0 + e1 + e2 + e3);
    pw[0][j] = e0 * inv; pw[1][j] = e1 * inv; pw[2][j] = e2 * inv; pw[3][j] = e3 * inv;
  }
  #pragma unroll
  for (int nt = 0; nt < 8; ++nt) {
    int n = (nt << 4) + lrow;
    #pragma unroll
    for (int j = 0; j < 4; ++j) {
      float acc = 0.f;
      #pragma unroll
      for (int s = 0; s < 4; ++s) {
        float f  = (s == 0) ? unpk(xcp0[nt][j >> 1], j & 1)
                            : bf2f((u32)xls[s - 1][crow0 + j][n]);
        float fn = (f - mean_[s][j]) * rstd_[s][j] * lngv[nt] + lnbv[nt];
        acc += pw[s][j] * fn;
      }
      __builtin_nontemporal_store(acc, &out[((r0w + crow0 + j) << 7) + n]);
    }
  }
}

extern "C" void kernel_launch(void* const* d_in, const int* in_sizes, int n_in,
                              void* d_out, int out_size, void* d_ws, size_t ws_size,
                              hipStream_t stream) {
  const float* h0        = (const float*)d_in[0];
  const float* h1        = (const float*)d_in[1];
  const float* h2        = (const float*)d_in[2];
  const float* h3        = (const float*)d_in[3];
  const float* proj_w    = (const float*)d_in[4];
  const float* proj_b    = (const float*)d_in[5];
  const float* ctx_w     = (const float*)d_in[6];
  const float* in_proj_w = (const float*)d_in[8];
  const float* in_proj_b = (const float*)d_in[9];
  const float* out_w     = (const float*)d_in[10];
  const float* out_b     = (const float*)d_in[11];
  const float* gate_w    = (const float*)d_in[12];
  const float* gate_b    = (const float*)d_in[13];
  const float* pool_w    = (const float*)d_in[14];
  const float* ln_g      = (const float*)d_in[16];
  const float* ln_b      = (const float*)d_in[17];
  u16* wp = (u16*)d_ws;

  pack_w<<<640, 256, 0, stream>>>(proj_w, in_proj_w, out_w, gate_w, wp);
  fused_k<<<NB / 16, 64, 0, stream>>>(h0, h1, h2, h3, wp,
                                      proj_b, ctx_w, in_proj_b, out_b, gate_b,
                                      pool_w, ln_g, ln_b, (float*)d_out);
}